// Round 1
// baseline (391.307 us; speedup 1.0000x reference)
//
#include <hip/hip_runtime.h>
#include <hip/hip_bf16.h>
#include <float.h>
#include <math.h>

#define RGB_H 288
#define RGB_W 256
#define NCH 10
#define HM_N 2
#define HM_S 640
#define MAX_DET_K 15
#define CAND_CAP 26000

// ---------------------------------------------------------------------------
// zero the per-map candidate counters (ws is poisoned 0xAA before every call)
// ---------------------------------------------------------------------------
__global__ __launch_bounds__(64) void zero_counters(int* counters) {
    if (threadIdx.x < HM_N) counters[threadIdx.x] = 0;
}

// ---------------------------------------------------------------------------
// Point painting: one thread per lidar point. Mirrors reference arithmetic:
//   world = L2W @ [x,y,z,1]; cam = W2C @ world; cam3=(cam1,-cam2,cam0);
//   c2 = K @ cam3; z = 1e-5f + c2[2]; u=int(c2[0]/z) (trunc); v likewise;
//   valid = (int(c2[2])>=0) & u in [0,256) & v in [0,288); last valid cam wins.
// Sequential fma accumulation in k-order matches BLAS/XLA dot rounding.
// Painted rows staged through LDS so global stores are coalesced.
// ---------------------------------------------------------------------------
__global__ __launch_bounds__(256) void paint_kernel(
    const float* __restrict__ lidar,
    const float* __restrict__ sems,
    const float* __restrict__ Km,
    const float* __restrict__ L2W,
    const float* __restrict__ W2C,
    float* __restrict__ out,
    int N)
{
    __shared__ float stage[256 * NCH];
    const int tid = threadIdx.x;
    const long long base = (long long)blockIdx.x * 256;
    const long long p = base + tid;

    float res[NCH];
#pragma unroll
    for (int c = 0; c < NCH; ++c) res[c] = 0.0f;

    if (p < N) {
        float4 pt = ((const float4*)lidar)[p];
        const float x = pt.x, y = pt.y, z = pt.z;

        // world = L2W @ [x,y,z,1]
        float w[3];
#pragma unroll
        for (int i = 0; i < 3; ++i) {
            float acc = L2W[4*i+0] * x;
            acc = fmaf(L2W[4*i+1], y, acc);
            acc = fmaf(L2W[4*i+2], z, acc);
            acc = fmaf(L2W[4*i+3], 1.0f, acc);
            w[i] = acc;
        }

        int sel = -1, su = 0, sv = 0;
#pragma unroll
        for (int i = 0; i < 3; ++i) {
            const float* W = W2C + 16 * i;
            float cam[3];
#pragma unroll
            for (int r = 0; r < 3; ++r) {
                float acc = W[4*r+0] * w[0];
                acc = fmaf(W[4*r+1], w[1], acc);
                acc = fmaf(W[4*r+2], w[2], acc);
                acc = fmaf(W[4*r+3], 1.0f, acc);
                cam[r] = acc;
            }
            const float c30 = cam[1], c31 = -cam[2], c32 = cam[0];
            float pr[3];
#pragma unroll
            for (int r = 0; r < 3; ++r) {
                float acc = Km[3*r+0] * c30;
                acc = fmaf(Km[3*r+1], c31, acc);
                acc = fmaf(Km[3*r+2], c32, acc);
                pr[r] = acc;
            }
            const float zz = 1e-5f + pr[2];
            const int u  = __float2int_rz(pr[0] / zz);
            const int v  = __float2int_rz(pr[1] / zz);
            const int zi = __float2int_rz(pr[2]);
            const bool valid = (zi >= 0) & (u >= 0) & (u < RGB_W)
                             & (v >= 0) & (v < RGB_H);
            if (valid) { sel = i; su = u; sv = v; }
        }
        if (sel >= 0) {
            const float* s = sems + (((long long)sel * NCH) * RGB_H + sv) * RGB_W + su;
#pragma unroll
            for (int c = 0; c < NCH; ++c)
                res[c] = s[(long long)c * RGB_H * RGB_W];
        }
    }

#pragma unroll
    for (int c = 0; c < NCH; ++c) stage[tid * NCH + c] = res[c];
    __syncthreads();

    const long long ob = base * NCH;
    const long long total = (long long)N * NCH;
#pragma unroll
    for (int k = 0; k < NCH; ++k) {
        long long idx = ob + (long long)k * 256 + tid;
        if (idx < total) out[idx] = stage[k * 256 + tid];
    }
}

// ---------------------------------------------------------------------------
// 7x7 SAME max-pool peak detection; peak iff !(windowmax > val).
// Candidates appended per map via device-scope atomics.
// ---------------------------------------------------------------------------
__global__ __launch_bounds__(256) void peaks_kernel(
    const float* __restrict__ hm,
    int* __restrict__ counters,
    float* __restrict__ cscore,
    int* __restrict__ cidx)
{
    const int u = blockIdx.x * 64 + threadIdx.x;
    const int v = blockIdx.y * 4 + threadIdx.y;
    const int m = blockIdx.z;
    if (u >= HM_S || v >= HM_S) return;

    const float* h = hm + (long long)m * HM_S * HM_S;
    const float val = h[v * HM_S + u];
    const int v0 = max(v - 3, 0), v1 = min(v + 3, HM_S - 1);
    const int u0 = max(u - 3, 0), u1 = min(u + 3, HM_S - 1);
    float mx = -INFINITY;
    for (int vv = v0; vv <= v1; ++vv) {
        const float* row = h + vv * HM_S;
        for (int uu = u0; uu <= u1; ++uu)
            mx = fmaxf(mx, row[uu]);
    }
    if (!(mx > val)) {
        int pos = atomicAdd(&counters[m], 1);
        if (pos < CAND_CAP) {
            cscore[m * CAND_CAP + pos] = val;
            cidx[m * CAND_CAP + pos] = v * HM_S + u;
        }
    }
}

// ---------------------------------------------------------------------------
// Per-map top-15 over candidates. Tie-break: higher score, then LOWER index
// (jax lax.top_k semantics). One block per map; iterative argmax.
// ---------------------------------------------------------------------------
__global__ __launch_bounds__(256) void topk_kernel(
    const int* __restrict__ counters,
    float* __restrict__ cscore,
    const int* __restrict__ cidx,
    float* __restrict__ out_scores,
    float* __restrict__ out_locs)
{
    const int m = blockIdx.x;
    const int tid = threadIdx.x;
    const int n = min(counters[m], CAND_CAP);
    float* sc = cscore + m * CAND_CAP;
    const int* ix = cidx + m * CAND_CAP;

    __shared__ float ss[256];
    __shared__ int   si[256];
    __shared__ int   sp[256];

    for (int t = 0; t < MAX_DET_K; ++t) {
        float bs = -INFINITY;
        int bi = 0x7fffffff;
        int bp = -1;
        for (int j = tid; j < n; j += 256) {
            const float s = sc[j];
            const int   id = ix[j];
            if (s > bs || (s == bs && id < bi)) { bs = s; bi = id; bp = j; }
        }
        ss[tid] = bs; si[tid] = bi; sp[tid] = bp;
        __syncthreads();
        for (int off = 128; off > 0; off >>= 1) {
            if (tid < off) {
                const float so = ss[tid + off];
                const int   io = si[tid + off];
                if (so > ss[tid] || (so == ss[tid] && io < si[tid])) {
                    ss[tid] = so; si[tid] = io; sp[tid] = sp[tid + off];
                }
            }
            __syncthreads();
        }
        if (tid == 0) {
            out_scores[m * MAX_DET_K + t] = ss[0];
            out_locs[m * MAX_DET_K + t]   = (float)si[0];
            if (sp[0] >= 0) sc[sp[0]] = -INFINITY;  // remove winner
        }
        __syncthreads();
    }
}

extern "C" void kernel_launch(void* const* d_in, const int* in_sizes, int n_in,
                              void* d_out, int out_size, void* d_ws, size_t ws_size,
                              hipStream_t stream)
{
    const float* lidar = (const float*)d_in[0];
    const float* sems  = (const float*)d_in[1];
    const float* hm    = (const float*)d_in[2];
    const float* Km    = (const float*)d_in[3];
    const float* L2W   = (const float*)d_in[4];
    const float* W2C   = (const float*)d_in[5];
    float* out = (float*)d_out;
    const int N = in_sizes[0] / 4;

    // workspace layout
    int*   counters = (int*)d_ws;
    float* cscore   = (float*)((char*)d_ws + 16);
    int*   cidx     = (int*)((char*)d_ws + 16 + (size_t)HM_N * CAND_CAP * sizeof(float));

    zero_counters<<<1, 64, 0, stream>>>(counters);

    paint_kernel<<<(N + 255) / 256, 256, 0, stream>>>(
        lidar, sems, Km, L2W, W2C, out, N);

    dim3 pb(64, 4, 1), pg(HM_S / 64, HM_S / 4, HM_N);
    peaks_kernel<<<pg, pb, 0, stream>>>(hm, counters, cscore, cidx);

    float* out_scores = out + (long long)N * NCH;
    float* out_locs   = out_scores + HM_N * MAX_DET_K;
    topk_kernel<<<HM_N, 256, 0, stream>>>(counters, cscore, cidx, out_scores, out_locs);
}

// Round 2
// 300.624 us; speedup vs baseline: 1.3016x; 1.3016x over previous
//
#include <hip/hip_runtime.h>
#include <hip/hip_bf16.h>
#include <float.h>
#include <math.h>

#define RGB_H 288
#define RGB_W 256
#define NCH 10
#define NCH_PAD 12
#define HM_N 2
#define HM_S 640
#define MAX_DET_K 15
#define CAND_CAP 26000
#define NB1 64                       // stage-1 blocks per map
#define CHUNK ((CAND_CAP + NB1 - 1) / NB1)   // 407 candidates per stage-1 block

// ---------------- ws layout ----------------
// [0,16)        : counters (2 ints)
// [16, +208000) : cscore   (2 x 26000 f32)
// [+208000)     : cidx     (2 x 26000 i32)
// [+7680)       : s1score  (2 x 64 x 15 f32)
// [+7680)       : s1idx    (2 x 64 x 15 i32)
// [...]         : psems    (3 x 288 x 256 x 12 f32) -- optional (ws permitting)
#define WS_CSCORE   16
#define WS_CIDX     (WS_CSCORE + HM_N * CAND_CAP * 4)
#define WS_S1SCORE  (WS_CIDX   + HM_N * CAND_CAP * 4)
#define WS_S1IDX    (WS_S1SCORE + HM_N * NB1 * MAX_DET_K * 4)
#define WS_PSEMS    (WS_S1IDX  + HM_N * NB1 * MAX_DET_K * 4)
#define PSEMS_BYTES ((size_t)3 * RGB_H * RGB_W * NCH_PAD * 4)

__global__ __launch_bounds__(64) void zero_counters(int* counters) {
    if (threadIdx.x < HM_N) counters[threadIdx.x] = 0;
}

// ---------------------------------------------------------------------------
// sems [cam][c][v][u] -> psems [cam][v][u][c] (c padded to 12 for f4 align).
// Pure data movement; numerics untouched.
// ---------------------------------------------------------------------------
__global__ __launch_bounds__(256) void transpose_sems(
    const float* __restrict__ sems, float* __restrict__ ps)
{
    const int t = blockIdx.x * 256 + threadIdx.x;
    const int total = 3 * RGB_H * RGB_W;
    if (t >= total) return;
    const int u = t & (RGB_W - 1);
    const int v = (t >> 8) % RGB_H;
    const int cam = t / (RGB_H * RGB_W);
    float vals[NCH_PAD];
#pragma unroll
    for (int c = 0; c < NCH; ++c)
        vals[c] = sems[(((long long)cam * NCH + c) * RGB_H + v) * RGB_W + u];
    vals[10] = 0.0f; vals[11] = 0.0f;
    float4* dst = (float4*)(ps + (size_t)t * NCH_PAD);
    dst[0] = make_float4(vals[0], vals[1], vals[2], vals[3]);
    dst[1] = make_float4(vals[4], vals[5], vals[6], vals[7]);
    dst[2] = make_float4(vals[8], vals[9], vals[10], vals[11]);
}

// ---------------------------------------------------------------------------
// Point painting (arithmetic identical to R1 — do not touch rounding).
// Gather path: 3x float4 from channel-contiguous psems when available.
// ---------------------------------------------------------------------------
__global__ __launch_bounds__(256) void paint_kernel(
    const float* __restrict__ lidar,
    const float* __restrict__ sems,
    const float* __restrict__ psems,
    int use_ps,
    const float* __restrict__ Km,
    const float* __restrict__ L2W,
    const float* __restrict__ W2C,
    float* __restrict__ out,
    int N)
{
    __shared__ float stage[256 * NCH];
    const int tid = threadIdx.x;
    const long long base = (long long)blockIdx.x * 256;
    const long long p = base + tid;

    float res[NCH];
#pragma unroll
    for (int c = 0; c < NCH; ++c) res[c] = 0.0f;

    if (p < N) {
        float4 pt = ((const float4*)lidar)[p];
        const float x = pt.x, y = pt.y, z = pt.z;

        float w[3];
#pragma unroll
        for (int i = 0; i < 3; ++i) {
            float acc = L2W[4*i+0] * x;
            acc = fmaf(L2W[4*i+1], y, acc);
            acc = fmaf(L2W[4*i+2], z, acc);
            acc = fmaf(L2W[4*i+3], 1.0f, acc);
            w[i] = acc;
        }

        int sel = -1, su = 0, sv = 0;
#pragma unroll
        for (int i = 0; i < 3; ++i) {
            const float* W = W2C + 16 * i;
            float cam[3];
#pragma unroll
            for (int r = 0; r < 3; ++r) {
                float acc = W[4*r+0] * w[0];
                acc = fmaf(W[4*r+1], w[1], acc);
                acc = fmaf(W[4*r+2], w[2], acc);
                acc = fmaf(W[4*r+3], 1.0f, acc);
                cam[r] = acc;
            }
            const float c30 = cam[1], c31 = -cam[2], c32 = cam[0];
            float pr[3];
#pragma unroll
            for (int r = 0; r < 3; ++r) {
                float acc = Km[3*r+0] * c30;
                acc = fmaf(Km[3*r+1], c31, acc);
                acc = fmaf(Km[3*r+2], c32, acc);
                pr[r] = acc;
            }
            const float zz = 1e-5f + pr[2];
            const int u  = __float2int_rz(pr[0] / zz);
            const int v  = __float2int_rz(pr[1] / zz);
            const int zi = __float2int_rz(pr[2]);
            const bool valid = (zi >= 0) & (u >= 0) & (u < RGB_W)
                             & (v >= 0) & (v < RGB_H);
            if (valid) { sel = i; su = u; sv = v; }
        }
        if (sel >= 0) {
            if (use_ps) {
                const long long pix = ((long long)sel * RGB_H + sv) * RGB_W + su;
                const float4* g = (const float4*)(psems + pix * NCH_PAD);
                float4 a = g[0], b = g[1], cc = g[2];
                res[0]=a.x; res[1]=a.y; res[2]=a.z; res[3]=a.w;
                res[4]=b.x; res[5]=b.y; res[6]=b.z; res[7]=b.w;
                res[8]=cc.x; res[9]=cc.y;
            } else {
                const float* s = sems + (((long long)sel * NCH) * RGB_H + sv) * RGB_W + su;
#pragma unroll
                for (int c = 0; c < NCH; ++c)
                    res[c] = s[(long long)c * RGB_H * RGB_W];
            }
        }
    }

#pragma unroll
    for (int c = 0; c < NCH; ++c) stage[tid * NCH + c] = res[c];
    __syncthreads();

    const long long ob = base * NCH;
    const long long total = (long long)N * NCH;
#pragma unroll
    for (int k = 0; k < NCH; ++k) {
        long long idx = ob + (long long)k * 256 + tid;
        if (idx < total) out[idx] = stage[k * 256 + tid];
    }
}

// ---------------------------------------------------------------------------
// Separable 7x7 SAME max-pool peak detection, LDS-tiled.
// Tile 64x16 per block (+3 halo). Peak iff !(windowmax > val).
// ---------------------------------------------------------------------------
#define TW 64
#define TH 16
#define SW (TW + 6)   // 70
#define SP 72         // padded LDS row stride
#define SH (TH + 6)   // 22

__global__ __launch_bounds__(256) void peaks_kernel(
    const float* __restrict__ hm,
    int* __restrict__ counters,
    float* __restrict__ cscore,
    int* __restrict__ cidx)
{
    __shared__ float sA[SH * SP];
    __shared__ float hx[SH * TW];

    const int tx = threadIdx.x;   // 0..63
    const int ty = threadIdx.y;   // 0..3
    const int gx0 = blockIdx.x * TW;
    const int gy0 = blockIdx.y * TH;
    const int m = blockIdx.z;
    const float* h = hm + (long long)m * HM_S * HM_S;

    // load tile + halo, -inf outside image (== SAME padding w/ -inf init)
    for (int yy = ty; yy < SH; yy += 4) {
        const int gv = gy0 + yy - 3;
        const bool vok = (gv >= 0) & (gv < HM_S);
        for (int xx = tx; xx < SW; xx += 64) {
            const int gu = gx0 + xx - 3;
            float val = -INFINITY;
            if (vok & (gu >= 0) & (gu < HM_S)) val = h[gv * HM_S + gu];
            sA[yy * SP + xx] = val;
        }
    }
    __syncthreads();

    // horizontal max-7
    for (int yy = ty; yy < SH; yy += 4) {
        const float* r = sA + yy * SP + tx;
        float mx = r[0];
#pragma unroll
        for (int k = 1; k < 7; ++k) mx = fmaxf(mx, r[k]);
        hx[yy * TW + tx] = mx;
    }
    __syncthreads();

    // vertical max-7 + peak test
    for (int ry = ty; ry < TH; ry += 4) {
        const float val = sA[(ry + 3) * SP + tx + 3];
        float mx = hx[ry * TW + tx];
#pragma unroll
        for (int k = 1; k < 7; ++k) mx = fmaxf(mx, hx[(ry + k) * TW + tx]);
        if (!(mx > val)) {
            int pos = atomicAdd(&counters[m], 1);
            if (pos < CAND_CAP) {
                cscore[m * CAND_CAP + pos] = val;
                cidx[m * CAND_CAP + pos] = (gy0 + ry) * HM_S + (gx0 + tx);
            }
        }
    }
}

// ---------------------------------------------------------------------------
// Top-15 stage 1: 64 blocks per map, each selects top-15 of its slice in LDS.
// Tie-break everywhere: higher score, then lower index.
// ---------------------------------------------------------------------------
__global__ __launch_bounds__(256) void topk_stage1(
    const int* __restrict__ counters,
    const float* __restrict__ cscore,
    const int* __restrict__ cidx,
    float* __restrict__ s1score,
    int* __restrict__ s1idx)
{
    const int b = blockIdx.x;
    const int m = blockIdx.y;
    const int tid = threadIdx.x;
    const int n = min(counters[m], CAND_CAP);
    const int start = b * CHUNK;
    const int cnt = max(0, min(n - start, CHUNK));

    __shared__ float ls[CHUNK];
    __shared__ int   li[CHUNK];
    __shared__ float ss[256];
    __shared__ int   si[256];
    __shared__ int   sp[256];

    for (int j = tid; j < CHUNK; j += 256) {
        ls[j] = (j < cnt) ? cscore[m * CAND_CAP + start + j] : -INFINITY;
        li[j] = (j < cnt) ? cidx[m * CAND_CAP + start + j] : 0x7fffffff;
    }
    __syncthreads();

    for (int t = 0; t < MAX_DET_K; ++t) {
        float bs = -INFINITY; int bi = 0x7fffffff; int bp = -1;
        for (int j = tid; j < CHUNK; j += 256) {
            const float s = ls[j]; const int id = li[j];
            if (s > bs || (s == bs && id < bi)) { bs = s; bi = id; bp = j; }
        }
        ss[tid] = bs; si[tid] = bi; sp[tid] = bp;
        __syncthreads();
        for (int off = 128; off > 0; off >>= 1) {
            if (tid < off) {
                const float so = ss[tid + off]; const int io = si[tid + off];
                if (so > ss[tid] || (so == ss[tid] && io < si[tid])) {
                    ss[tid] = so; si[tid] = io; sp[tid] = sp[tid + off];
                }
            }
            __syncthreads();
        }
        if (tid == 0) {
            s1score[(m * NB1 + b) * MAX_DET_K + t] = ss[0];
            s1idx[(m * NB1 + b) * MAX_DET_K + t]   = si[0];
            if (sp[0] >= 0) ls[sp[0]] = -INFINITY;
        }
        __syncthreads();
    }
}

// ---------------------------------------------------------------------------
// Top-15 stage 2: one block per map merges 64x15 = 960 entries.
// ---------------------------------------------------------------------------
#define S2N (NB1 * MAX_DET_K)   // 960

__global__ __launch_bounds__(256) void topk_stage2(
    const float* __restrict__ s1score,
    const int* __restrict__ s1idx,
    float* __restrict__ out_scores,
    float* __restrict__ out_locs)
{
    const int m = blockIdx.x;
    const int tid = threadIdx.x;

    __shared__ float ls[S2N];
    __shared__ int   li[S2N];
    __shared__ float ss[256];
    __shared__ int   si[256];
    __shared__ int   sp[256];

    for (int j = tid; j < S2N; j += 256) {
        ls[j] = s1score[m * S2N + j];
        li[j] = s1idx[m * S2N + j];
    }
    __syncthreads();

    for (int t = 0; t < MAX_DET_K; ++t) {
        float bs = -INFINITY; int bi = 0x7fffffff; int bp = -1;
        for (int j = tid; j < S2N; j += 256) {
            const float s = ls[j]; const int id = li[j];
            if (s > bs || (s == bs && id < bi)) { bs = s; bi = id; bp = j; }
        }
        ss[tid] = bs; si[tid] = bi; sp[tid] = bp;
        __syncthreads();
        for (int off = 128; off > 0; off >>= 1) {
            if (tid < off) {
                const float so = ss[tid + off]; const int io = si[tid + off];
                if (so > ss[tid] || (so == ss[tid] && io < si[tid])) {
                    ss[tid] = so; si[tid] = io; sp[tid] = sp[tid + off];
                }
            }
            __syncthreads();
        }
        if (tid == 0) {
            out_scores[m * MAX_DET_K + t] = ss[0];
            out_locs[m * MAX_DET_K + t]   = (float)si[0];
            if (sp[0] >= 0) ls[sp[0]] = -INFINITY;
        }
        __syncthreads();
    }
}

extern "C" void kernel_launch(void* const* d_in, const int* in_sizes, int n_in,
                              void* d_out, int out_size, void* d_ws, size_t ws_size,
                              hipStream_t stream)
{
    const float* lidar = (const float*)d_in[0];
    const float* sems  = (const float*)d_in[1];
    const float* hm    = (const float*)d_in[2];
    const float* Km    = (const float*)d_in[3];
    const float* L2W   = (const float*)d_in[4];
    const float* W2C   = (const float*)d_in[5];
    float* out = (float*)d_out;
    const int N = in_sizes[0] / 4;

    char* ws = (char*)d_ws;
    int*   counters = (int*)ws;
    float* cscore   = (float*)(ws + WS_CSCORE);
    int*   cidx     = (int*)(ws + WS_CIDX);
    float* s1score  = (float*)(ws + WS_S1SCORE);
    int*   s1idx    = (int*)(ws + WS_S1IDX);
    float* psems    = (float*)(ws + WS_PSEMS);
    const int use_ps = (ws_size >= (size_t)WS_PSEMS + PSEMS_BYTES) ? 1 : 0;

    zero_counters<<<1, 64, 0, stream>>>(counters);

    if (use_ps) {
        const int tp_total = 3 * RGB_H * RGB_W;
        transpose_sems<<<(tp_total + 255) / 256, 256, 0, stream>>>(sems, psems);
    }

    paint_kernel<<<(N + 255) / 256, 256, 0, stream>>>(
        lidar, sems, psems, use_ps, Km, L2W, W2C, out, N);

    dim3 pb(64, 4, 1), pg(HM_S / TW, HM_S / TH, HM_N);
    peaks_kernel<<<pg, pb, 0, stream>>>(hm, counters, cscore, cidx);

    topk_stage1<<<dim3(NB1, HM_N), 256, 0, stream>>>(counters, cscore, cidx, s1score, s1idx);

    float* out_scores = out + (long long)N * NCH;
    float* out_locs   = out_scores + HM_N * MAX_DET_K;
    topk_stage2<<<HM_N, 256, 0, stream>>>(s1score, s1idx, out_scores, out_locs);
}

// Round 3
// 199.341 us; speedup vs baseline: 1.9630x; 1.5081x over previous
//
#include <hip/hip_runtime.h>
#include <hip/hip_bf16.h>
#include <float.h>
#include <math.h>

#define RGB_H 288
#define RGB_W 256
#define NCH 10
#define NCH_PAD 12
#define HM_N 2
#define HM_S 640
#define MAX_DET_K 15
#define CAND_CAP 26000
#define NB1 64                       // stage-1 blocks per map
#define CHUNK ((CAND_CAP + NB1 - 1) / NB1)   // 407 candidates per stage-1 block

// ---------------- ws layout ----------------
#define WS_CSCORE   16
#define WS_CIDX     (WS_CSCORE + HM_N * CAND_CAP * 4)
#define WS_S1SCORE  (WS_CIDX   + HM_N * CAND_CAP * 4)
#define WS_S1IDX    (WS_S1SCORE + HM_N * NB1 * MAX_DET_K * 4)
#define WS_PSEMS    (WS_S1IDX  + HM_N * NB1 * MAX_DET_K * 4)
#define PSEMS_BYTES ((size_t)3 * RGB_H * RGB_W * NCH_PAD * 4)

__global__ __launch_bounds__(64) void zero_counters(int* counters) {
    if (threadIdx.x < HM_N) counters[threadIdx.x] = 0;
}

// ---------------------------------------------------------------------------
// sems [cam][c][v][u] -> psems [cam][v][u][c] (c padded to 12 for f4 align).
// ---------------------------------------------------------------------------
__global__ __launch_bounds__(256) void transpose_sems(
    const float* __restrict__ sems, float* __restrict__ ps)
{
    const int t = blockIdx.x * 256 + threadIdx.x;
    const int total = 3 * RGB_H * RGB_W;
    if (t >= total) return;
    const int u = t & (RGB_W - 1);
    const int v = (t >> 8) % RGB_H;
    const int cam = t / (RGB_H * RGB_W);
    float vals[NCH_PAD];
#pragma unroll
    for (int c = 0; c < NCH; ++c)
        vals[c] = sems[(((long long)cam * NCH + c) * RGB_H + v) * RGB_W + u];
    vals[10] = 0.0f; vals[11] = 0.0f;
    float4* dst = (float4*)(ps + (size_t)t * NCH_PAD);
    dst[0] = make_float4(vals[0], vals[1], vals[2], vals[3]);
    dst[1] = make_float4(vals[4], vals[5], vals[6], vals[7]);
    dst[2] = make_float4(vals[8], vals[9], vals[10], vals[11]);
}

// ---------------------------------------------------------------------------
// Point painting (arithmetic identical to R1 — do not touch rounding).
// ---------------------------------------------------------------------------
__global__ __launch_bounds__(256) void paint_kernel(
    const float* __restrict__ lidar,
    const float* __restrict__ sems,
    const float* __restrict__ psems,
    int use_ps,
    const float* __restrict__ Km,
    const float* __restrict__ L2W,
    const float* __restrict__ W2C,
    float* __restrict__ out,
    int N)
{
    __shared__ float stage[256 * NCH];
    const int tid = threadIdx.x;
    const long long base = (long long)blockIdx.x * 256;
    const long long p = base + tid;

    float res[NCH];
#pragma unroll
    for (int c = 0; c < NCH; ++c) res[c] = 0.0f;

    if (p < N) {
        float4 pt = ((const float4*)lidar)[p];
        const float x = pt.x, y = pt.y, z = pt.z;

        float w[3];
#pragma unroll
        for (int i = 0; i < 3; ++i) {
            float acc = L2W[4*i+0] * x;
            acc = fmaf(L2W[4*i+1], y, acc);
            acc = fmaf(L2W[4*i+2], z, acc);
            acc = fmaf(L2W[4*i+3], 1.0f, acc);
            w[i] = acc;
        }

        int sel = -1, su = 0, sv = 0;
#pragma unroll
        for (int i = 0; i < 3; ++i) {
            const float* W = W2C + 16 * i;
            float cam[3];
#pragma unroll
            for (int r = 0; r < 3; ++r) {
                float acc = W[4*r+0] * w[0];
                acc = fmaf(W[4*r+1], w[1], acc);
                acc = fmaf(W[4*r+2], w[2], acc);
                acc = fmaf(W[4*r+3], 1.0f, acc);
                cam[r] = acc;
            }
            const float c30 = cam[1], c31 = -cam[2], c32 = cam[0];
            float pr[3];
#pragma unroll
            for (int r = 0; r < 3; ++r) {
                float acc = Km[3*r+0] * c30;
                acc = fmaf(Km[3*r+1], c31, acc);
                acc = fmaf(Km[3*r+2], c32, acc);
                pr[r] = acc;
            }
            const float zz = 1e-5f + pr[2];
            const int u  = __float2int_rz(pr[0] / zz);
            const int v  = __float2int_rz(pr[1] / zz);
            const int zi = __float2int_rz(pr[2]);
            const bool valid = (zi >= 0) & (u >= 0) & (u < RGB_W)
                             & (v >= 0) & (v < RGB_H);
            if (valid) { sel = i; su = u; sv = v; }
        }
        if (sel >= 0) {
            if (use_ps) {
                const long long pix = ((long long)sel * RGB_H + sv) * RGB_W + su;
                const float4* g = (const float4*)(psems + pix * NCH_PAD);
                float4 a = g[0], b = g[1], cc = g[2];
                res[0]=a.x; res[1]=a.y; res[2]=a.z; res[3]=a.w;
                res[4]=b.x; res[5]=b.y; res[6]=b.z; res[7]=b.w;
                res[8]=cc.x; res[9]=cc.y;
            } else {
                const float* s = sems + (((long long)sel * NCH) * RGB_H + sv) * RGB_W + su;
#pragma unroll
                for (int c = 0; c < NCH; ++c)
                    res[c] = s[(long long)c * RGB_H * RGB_W];
            }
        }
    }

#pragma unroll
    for (int c = 0; c < NCH; ++c) stage[tid * NCH + c] = res[c];
    __syncthreads();

    const long long ob = base * NCH;
    const long long total = (long long)N * NCH;
#pragma unroll
    for (int k = 0; k < NCH; ++k) {
        long long idx = ob + (long long)k * 256 + tid;
        if (idx < total) out[idx] = stage[k * 256 + tid];
    }
}

// ---------------------------------------------------------------------------
// Separable 7x7 SAME max-pool peak detection, LDS-tiled, with BLOCK-LOCAL
// candidate aggregation: peaks land in an LDS list (LDS atomics), then ONE
// device atomicAdd per block reserves a contiguous range, then coalesced
// copy-out. This removes the same-address device-atomic serialization that
// capped R1/R2 at ~120 us.
// ---------------------------------------------------------------------------
#define TW 64
#define TH 16
#define SW (TW + 6)   // 70
#define SP 72         // padded LDS row stride
#define SH (TH + 6)   // 22

__global__ __launch_bounds__(256) void peaks_kernel(
    const float* __restrict__ hm,
    int* __restrict__ counters,
    float* __restrict__ cscore,
    int* __restrict__ cidx)
{
    __shared__ float sA[SH * SP];
    __shared__ float hx[SH * TW];
    __shared__ float lsc[TW * TH];
    __shared__ int   lix[TW * TH];
    __shared__ int   lcnt;
    __shared__ int   lbase;

    const int tx = threadIdx.x;   // 0..63
    const int ty = threadIdx.y;   // 0..3
    const int flat = ty * 64 + tx;
    const int gx0 = blockIdx.x * TW;
    const int gy0 = blockIdx.y * TH;
    const int m = blockIdx.z;
    const float* h = hm + (long long)m * HM_S * HM_S;

    if (flat == 0) lcnt = 0;

    // load tile + halo, -inf outside image
    for (int yy = ty; yy < SH; yy += 4) {
        const int gv = gy0 + yy - 3;
        const bool vok = (gv >= 0) & (gv < HM_S);
        for (int xx = tx; xx < SW; xx += 64) {
            const int gu = gx0 + xx - 3;
            float val = -INFINITY;
            if (vok & (gu >= 0) & (gu < HM_S)) val = h[gv * HM_S + gu];
            sA[yy * SP + xx] = val;
        }
    }
    __syncthreads();

    // horizontal max-7
    for (int yy = ty; yy < SH; yy += 4) {
        const float* r = sA + yy * SP + tx;
        float mx = r[0];
#pragma unroll
        for (int k = 1; k < 7; ++k) mx = fmaxf(mx, r[k]);
        hx[yy * TW + tx] = mx;
    }
    __syncthreads();

    // vertical max-7 + peak test -> LDS list
    for (int ry = ty; ry < TH; ry += 4) {
        const float val = sA[(ry + 3) * SP + tx + 3];
        float mx = hx[ry * TW + tx];
#pragma unroll
        for (int k = 1; k < 7; ++k) mx = fmaxf(mx, hx[(ry + k) * TW + tx]);
        if (!(mx > val)) {
            int pos = atomicAdd(&lcnt, 1);   // LDS atomic
            lsc[pos] = val;
            lix[pos] = (gy0 + ry) * HM_S + (gx0 + tx);
        }
    }
    __syncthreads();

    if (flat == 0) lbase = atomicAdd(&counters[m], lcnt);  // ONE per block
    __syncthreads();

    const int n = lcnt;
    const int b0 = lbase;
    for (int j = flat; j < n; j += 256) {
        const int g = b0 + j;
        if (g < CAND_CAP) {
            cscore[m * CAND_CAP + g] = lsc[j];
            cidx[m * CAND_CAP + g]   = lix[j];
        }
    }
}

// ---------------------------------------------------------------------------
// Top-15 stage 1: 64 blocks per map, each selects top-15 of its slice in LDS.
// ---------------------------------------------------------------------------
__global__ __launch_bounds__(256) void topk_stage1(
    const int* __restrict__ counters,
    const float* __restrict__ cscore,
    const int* __restrict__ cidx,
    float* __restrict__ s1score,
    int* __restrict__ s1idx)
{
    const int b = blockIdx.x;
    const int m = blockIdx.y;
    const int tid = threadIdx.x;
    const int n = min(counters[m], CAND_CAP);
    const int start = b * CHUNK;
    const int cnt = max(0, min(n - start, CHUNK));

    __shared__ float ls[CHUNK];
    __shared__ int   li[CHUNK];
    __shared__ float ss[256];
    __shared__ int   si[256];
    __shared__ int   sp[256];

    for (int j = tid; j < CHUNK; j += 256) {
        ls[j] = (j < cnt) ? cscore[m * CAND_CAP + start + j] : -INFINITY;
        li[j] = (j < cnt) ? cidx[m * CAND_CAP + start + j] : 0x7fffffff;
    }
    __syncthreads();

    for (int t = 0; t < MAX_DET_K; ++t) {
        float bs = -INFINITY; int bi = 0x7fffffff; int bp = -1;
        for (int j = tid; j < CHUNK; j += 256) {
            const float s = ls[j]; const int id = li[j];
            if (s > bs || (s == bs && id < bi)) { bs = s; bi = id; bp = j; }
        }
        ss[tid] = bs; si[tid] = bi; sp[tid] = bp;
        __syncthreads();
        for (int off = 128; off > 0; off >>= 1) {
            if (tid < off) {
                const float so = ss[tid + off]; const int io = si[tid + off];
                if (so > ss[tid] || (so == ss[tid] && io < si[tid])) {
                    ss[tid] = so; si[tid] = io; sp[tid] = sp[tid + off];
                }
            }
            __syncthreads();
        }
        if (tid == 0) {
            s1score[(m * NB1 + b) * MAX_DET_K + t] = ss[0];
            s1idx[(m * NB1 + b) * MAX_DET_K + t]   = si[0];
            if (sp[0] >= 0) ls[sp[0]] = -INFINITY;
        }
        __syncthreads();
    }
}

// ---------------------------------------------------------------------------
// Top-15 stage 2: one block per map merges 64x15 = 960 entries.
// ---------------------------------------------------------------------------
#define S2N (NB1 * MAX_DET_K)   // 960

__global__ __launch_bounds__(256) void topk_stage2(
    const float* __restrict__ s1score,
    const int* __restrict__ s1idx,
    float* __restrict__ out_scores,
    float* __restrict__ out_locs)
{
    const int m = blockIdx.x;
    const int tid = threadIdx.x;

    __shared__ float ls[S2N];
    __shared__ int   li[S2N];
    __shared__ float ss[256];
    __shared__ int   si[256];
    __shared__ int   sp[256];

    for (int j = tid; j < S2N; j += 256) {
        ls[j] = s1score[m * S2N + j];
        li[j] = s1idx[m * S2N + j];
    }
    __syncthreads();

    for (int t = 0; t < MAX_DET_K; ++t) {
        float bs = -INFINITY; int bi = 0x7fffffff; int bp = -1;
        for (int j = tid; j < S2N; j += 256) {
            const float s = ls[j]; const int id = li[j];
            if (s > bs || (s == bs && id < bi)) { bs = s; bi = id; bp = j; }
        }
        ss[tid] = bs; si[tid] = bi; sp[tid] = bp;
        __syncthreads();
        for (int off = 128; off > 0; off >>= 1) {
            if (tid < off) {
                const float so = ss[tid + off]; const int io = si[tid + off];
                if (so > ss[tid] || (so == ss[tid] && io < si[tid])) {
                    ss[tid] = so; si[tid] = io; sp[tid] = sp[tid + off];
                }
            }
            __syncthreads();
        }
        if (tid == 0) {
            out_scores[m * MAX_DET_K + t] = ss[0];
            out_locs[m * MAX_DET_K + t]   = (float)si[0];
            if (sp[0] >= 0) ls[sp[0]] = -INFINITY;
        }
        __syncthreads();
    }
}

extern "C" void kernel_launch(void* const* d_in, const int* in_sizes, int n_in,
                              void* d_out, int out_size, void* d_ws, size_t ws_size,
                              hipStream_t stream)
{
    const float* lidar = (const float*)d_in[0];
    const float* sems  = (const float*)d_in[1];
    const float* hm    = (const float*)d_in[2];
    const float* Km    = (const float*)d_in[3];
    const float* L2W   = (const float*)d_in[4];
    const float* W2C   = (const float*)d_in[5];
    float* out = (float*)d_out;
    const int N = in_sizes[0] / 4;

    char* ws = (char*)d_ws;
    int*   counters = (int*)ws;
    float* cscore   = (float*)(ws + WS_CSCORE);
    int*   cidx     = (int*)(ws + WS_CIDX);
    float* s1score  = (float*)(ws + WS_S1SCORE);
    int*   s1idx    = (int*)(ws + WS_S1IDX);
    float* psems    = (float*)(ws + WS_PSEMS);
    const int use_ps = (ws_size >= (size_t)WS_PSEMS + PSEMS_BYTES) ? 1 : 0;

    zero_counters<<<1, 64, 0, stream>>>(counters);

    if (use_ps) {
        const int tp_total = 3 * RGB_H * RGB_W;
        transpose_sems<<<(tp_total + 255) / 256, 256, 0, stream>>>(sems, psems);
    }

    paint_kernel<<<(N + 255) / 256, 256, 0, stream>>>(
        lidar, sems, psems, use_ps, Km, L2W, W2C, out, N);

    dim3 pb(64, 4, 1), pg(HM_S / TW, HM_S / TH, HM_N);
    peaks_kernel<<<pg, pb, 0, stream>>>(hm, counters, cscore, cidx);

    topk_stage1<<<dim3(NB1, HM_N), 256, 0, stream>>>(counters, cscore, cidx, s1score, s1idx);

    float* out_scores = out + (long long)N * NCH;
    float* out_locs   = out_scores + HM_N * MAX_DET_K;
    topk_stage2<<<HM_N, 256, 0, stream>>>(s1score, s1idx, out_scores, out_locs);
}

// Round 5
// 187.038 us; speedup vs baseline: 2.0921x; 1.0658x over previous
//
#include <hip/hip_runtime.h>
#include <hip/hip_bf16.h>
#include <float.h>
#include <math.h>

#define RGB_H 288
#define RGB_W 256
#define NCH 10
#define NCH_PAD 12
#define HM_N 2
#define HM_S 640
#define MAX_DET_K 15

// native vector type (HIP float4 is a struct; nontemporal builtins need this)
typedef float f4 __attribute__((ext_vector_type(4)));

// peak tiles
#define TW 64
#define TH 16
#define SW (TW + 6)   // 70
#define SP 72         // padded LDS row stride
#define SH (TH + 6)   // 22
#define NTILE_X (HM_S / TW)              // 10
#define NTILE_Y (HM_S / TH)              // 40
#define TILES_PER_MAP (NTILE_X * NTILE_Y) // 400
#define S1N (TILES_PER_MAP * MAX_DET_K)   // 6000 entries per map

// ---------------- ws layout ----------------
#define WS_S1SCORE  0
#define WS_S1IDX    (WS_S1SCORE + HM_N * S1N * 4)
#define WS_PSEMS    ((WS_S1IDX + HM_N * S1N * 4 + 15) & ~15)
#define PSEMS_BYTES ((size_t)3 * RGB_H * RGB_W * NCH_PAD * 4)

// ---------------------------------------------------------------------------
// sems [cam][c][v][u] -> psems [cam][v][u][c] (c padded to 12 for f4 align).
// ---------------------------------------------------------------------------
__global__ __launch_bounds__(256) void transpose_sems(
    const float* __restrict__ sems, float* __restrict__ ps)
{
    const int t = blockIdx.x * 256 + threadIdx.x;
    const int total = 3 * RGB_H * RGB_W;
    if (t >= total) return;
    const int u = t & (RGB_W - 1);
    const int v = (t >> 8) % RGB_H;
    const int cam = t / (RGB_H * RGB_W);
    float vals[NCH_PAD];
#pragma unroll
    for (int c = 0; c < NCH; ++c)
        vals[c] = sems[(((long long)cam * NCH + c) * RGB_H + v) * RGB_W + u];
    vals[10] = 0.0f; vals[11] = 0.0f;
    f4* dst = (f4*)(ps + (size_t)t * NCH_PAD);
    dst[0] = (f4){vals[0], vals[1], vals[2], vals[3]};
    dst[1] = (f4){vals[4], vals[5], vals[6], vals[7]};
    dst[2] = (f4){vals[8], vals[9], vals[10], vals[11]};
}

// ---------------------------------------------------------------------------
// Point painting (projection arithmetic identical to R1 — do not touch).
// Streaming traffic (lidar in, painted out) uses nontemporal accesses so the
// gathered psems stays resident in L2. Output staged in LDS -> f4 stores.
// ---------------------------------------------------------------------------
__global__ __launch_bounds__(256) void paint_kernel(
    const float* __restrict__ lidar,
    const float* __restrict__ sems,
    const float* __restrict__ psems,
    int use_ps,
    const float* __restrict__ Km,
    const float* __restrict__ L2W,
    const float* __restrict__ W2C,
    float* __restrict__ out,
    int N)
{
    __shared__ __align__(16) float stage[256 * NCH];
    const int tid = threadIdx.x;
    const long long base = (long long)blockIdx.x * 256;
    const long long p = base + tid;

    float res[NCH];
#pragma unroll
    for (int c = 0; c < NCH; ++c) res[c] = 0.0f;

    if (p < N) {
        const f4 pt = __builtin_nontemporal_load(((const f4*)lidar) + p);
        const float x = pt.x, y = pt.y, z = pt.z;

        float w[3];
#pragma unroll
        for (int i = 0; i < 3; ++i) {
            float acc = L2W[4*i+0] * x;
            acc = fmaf(L2W[4*i+1], y, acc);
            acc = fmaf(L2W[4*i+2], z, acc);
            acc = fmaf(L2W[4*i+3], 1.0f, acc);
            w[i] = acc;
        }

        int sel = -1, su = 0, sv = 0;
#pragma unroll
        for (int i = 0; i < 3; ++i) {
            const float* W = W2C + 16 * i;
            float cam[3];
#pragma unroll
            for (int r = 0; r < 3; ++r) {
                float acc = W[4*r+0] * w[0];
                acc = fmaf(W[4*r+1], w[1], acc);
                acc = fmaf(W[4*r+2], w[2], acc);
                acc = fmaf(W[4*r+3], 1.0f, acc);
                cam[r] = acc;
            }
            const float c30 = cam[1], c31 = -cam[2], c32 = cam[0];
            float pr[3];
#pragma unroll
            for (int r = 0; r < 3; ++r) {
                float acc = Km[3*r+0] * c30;
                acc = fmaf(Km[3*r+1], c31, acc);
                acc = fmaf(Km[3*r+2], c32, acc);
                pr[r] = acc;
            }
            const float zz = 1e-5f + pr[2];
            const int u  = __float2int_rz(pr[0] / zz);
            const int v  = __float2int_rz(pr[1] / zz);
            const int zi = __float2int_rz(pr[2]);
            const bool valid = (zi >= 0) & (u >= 0) & (u < RGB_W)
                             & (v >= 0) & (v < RGB_H);
            if (valid) { sel = i; su = u; sv = v; }
        }
        if (sel >= 0) {
            if (use_ps) {
                const long long pix = ((long long)sel * RGB_H + sv) * RGB_W + su;
                const f4* g = (const f4*)(psems + pix * NCH_PAD);
                f4 a = g[0], b = g[1], cc = g[2];
                res[0]=a.x; res[1]=a.y; res[2]=a.z; res[3]=a.w;
                res[4]=b.x; res[5]=b.y; res[6]=b.z; res[7]=b.w;
                res[8]=cc.x; res[9]=cc.y;
            } else {
                const float* s = sems + (((long long)sel * NCH) * RGB_H + sv) * RGB_W + su;
#pragma unroll
                for (int c = 0; c < NCH; ++c)
                    res[c] = s[(long long)c * RGB_H * RGB_W];
            }
        }
    }

#pragma unroll
    for (int c = 0; c < NCH; ++c) stage[tid * NCH + c] = res[c];
    __syncthreads();

    // 256 points x 10 ch = 2560 floats = 640 f4 per block, coalesced + nt
    const f4* st4 = (const f4*)stage;
    const long long blockF4 = (long long)blockIdx.x * 640;
    const long long totalF4 = ((long long)N * NCH) >> 2;
    for (int j = tid; j < 640; j += 256) {
        const long long g = blockF4 + j;
        if (g < totalF4)
            __builtin_nontemporal_store(st4[j], ((f4*)out) + g);
    }
}

// ---------------------------------------------------------------------------
// Fused: separable 7x7 SAME max-pool peak detect + per-tile top-15.
// Each tile writes EXACTLY 15 (score,idx) entries to fixed slots (pad with
// -inf / INT_MAX). Local top-15 covers the global top-15, so no atomics,
// no counters, no candidate buffer. Tie-break: score desc, then idx asc.
// ---------------------------------------------------------------------------
__global__ __launch_bounds__(256) void peaks15_kernel(
    const float* __restrict__ hm,
    float* __restrict__ s1score,
    int* __restrict__ s1idx)
{
    __shared__ float sA[SH * SP];
    __shared__ float hx[SH * TW];
    __shared__ float lsc[TW * TH];
    __shared__ int   lix[TW * TH];
    __shared__ int   lcnt;

    const int tx = threadIdx.x;   // 0..63
    const int ty = threadIdx.y;   // 0..3
    const int flat = ty * 64 + tx;
    const int gx0 = blockIdx.x * TW;
    const int gy0 = blockIdx.y * TH;
    const int m = blockIdx.z;
    const float* h = hm + (long long)m * HM_S * HM_S;

    if (flat == 0) lcnt = 0;
    __syncthreads();

    for (int yy = ty; yy < SH; yy += 4) {
        const int gv = gy0 + yy - 3;
        const bool vok = (gv >= 0) & (gv < HM_S);
        for (int xx = tx; xx < SW; xx += 64) {
            const int gu = gx0 + xx - 3;
            float val = -INFINITY;
            if (vok & (gu >= 0) & (gu < HM_S)) val = h[gv * HM_S + gu];
            sA[yy * SP + xx] = val;
        }
    }
    __syncthreads();

    for (int yy = ty; yy < SH; yy += 4) {
        const float* r = sA + yy * SP + tx;
        float mx = r[0];
#pragma unroll
        for (int k = 1; k < 7; ++k) mx = fmaxf(mx, r[k]);
        hx[yy * TW + tx] = mx;
    }
    __syncthreads();

    for (int ry = ty; ry < TH; ry += 4) {
        const float val = sA[(ry + 3) * SP + tx + 3];
        float mx = hx[ry * TW + tx];
#pragma unroll
        for (int k = 1; k < 7; ++k) mx = fmaxf(mx, hx[(ry + k) * TW + tx]);
        if (!(mx > val)) {
            int pos = atomicAdd(&lcnt, 1);   // LDS atomic
            lsc[pos] = val;
            lix[pos] = (gy0 + ry) * HM_S + (gx0 + tx);
        }
    }
    __syncthreads();

    // wave 0: 15 x argmax over the (avg ~20, max 1024) local candidates
    if (flat < 64) {
        const int n = lcnt;
        const int tile = blockIdx.y * NTILE_X + blockIdx.x;
        const int slot0 = (m * TILES_PER_MAP + tile) * MAX_DET_K;
        for (int t = 0; t < MAX_DET_K; ++t) {
            float bs = -INFINITY; int bi = 0x7fffffff; int bp = -1;
            for (int j = flat; j < n; j += 64) {
                const float s = lsc[j]; const int id = lix[j];
                if (s > bs || (s == bs && id < bi)) { bs = s; bi = id; bp = j; }
            }
#pragma unroll
            for (int off = 32; off > 0; off >>= 1) {
                const float os = __shfl_down(bs, off);
                const int   oi = __shfl_down(bi, off);
                const int   op = __shfl_down(bp, off);
                if (os > bs || (os == bs && oi < bi)) { bs = os; bi = oi; bp = op; }
            }
            // broadcast winner to all lanes, mark it consumed
            bs = __shfl(bs, 0); bi = __shfl(bi, 0); bp = __shfl(bp, 0);
            if (flat == 0) {
                s1score[slot0 + t] = bs;
                s1idx[slot0 + t]   = bi;
            }
            if (flat == 0 && bp >= 0) lsc[bp] = -INFINITY;
        }
    }
}

// ---------------------------------------------------------------------------
// Final merge: one 1024-thread block per map over 400x15 = 6000 entries.
// ---------------------------------------------------------------------------
__global__ __launch_bounds__(1024) void merge_kernel(
    const float* __restrict__ s1score,
    const int* __restrict__ s1idx,
    float* __restrict__ out_scores,
    float* __restrict__ out_locs)
{
    const int m = blockIdx.x;
    const int tid = threadIdx.x;
    const int lane = tid & 63;
    const int wv = tid >> 6;     // 0..15

    __shared__ float ls[S1N];
    __shared__ int   li[S1N];
    __shared__ float ws[16];
    __shared__ int   wi[16];
    __shared__ int   wp[16];

    for (int j = tid; j < S1N; j += 1024) {
        ls[j] = s1score[m * S1N + j];
        li[j] = s1idx[m * S1N + j];
    }
    __syncthreads();

    for (int t = 0; t < MAX_DET_K; ++t) {
        float bs = -INFINITY; int bi = 0x7fffffff; int bp = -1;
        for (int j = tid; j < S1N; j += 1024) {
            const float s = ls[j]; const int id = li[j];
            if (s > bs || (s == bs && id < bi)) { bs = s; bi = id; bp = j; }
        }
#pragma unroll
        for (int off = 32; off > 0; off >>= 1) {
            const float os = __shfl_down(bs, off);
            const int   oi = __shfl_down(bi, off);
            const int   op = __shfl_down(bp, off);
            if (os > bs || (os == bs && oi < bi)) { bs = os; bi = oi; bp = op; }
        }
        if (lane == 0) { ws[wv] = bs; wi[wv] = bi; wp[wv] = bp; }
        __syncthreads();
        if (tid < 64) {
            bs = (tid < 16) ? ws[tid] : -INFINITY;
            bi = (tid < 16) ? wi[tid] : 0x7fffffff;
            bp = (tid < 16) ? wp[tid] : -1;
#pragma unroll
            for (int off = 8; off > 0; off >>= 1) {
                const float os = __shfl_down(bs, off);
                const int   oi = __shfl_down(bi, off);
                const int   op = __shfl_down(bp, off);
                if (os > bs || (os == bs && oi < bi)) { bs = os; bi = oi; bp = op; }
            }
            if (tid == 0) {
                out_scores[m * MAX_DET_K + t] = bs;
                out_locs[m * MAX_DET_K + t]   = (float)bi;
                if (bp >= 0) ls[bp] = -INFINITY;
            }
        }
        __syncthreads();
    }
}

extern "C" void kernel_launch(void* const* d_in, const int* in_sizes, int n_in,
                              void* d_out, int out_size, void* d_ws, size_t ws_size,
                              hipStream_t stream)
{
    const float* lidar = (const float*)d_in[0];
    const float* sems  = (const float*)d_in[1];
    const float* hm    = (const float*)d_in[2];
    const float* Km    = (const float*)d_in[3];
    const float* L2W   = (const float*)d_in[4];
    const float* W2C   = (const float*)d_in[5];
    float* out = (float*)d_out;
    const int N = in_sizes[0] / 4;

    char* ws = (char*)d_ws;
    float* s1score = (float*)(ws + WS_S1SCORE);
    int*   s1idx   = (int*)(ws + WS_S1IDX);
    float* psems   = (float*)(ws + WS_PSEMS);
    const int use_ps = (ws_size >= (size_t)WS_PSEMS + PSEMS_BYTES) ? 1 : 0;

    if (use_ps) {
        const int tp_total = 3 * RGB_H * RGB_W;
        transpose_sems<<<(tp_total + 255) / 256, 256, 0, stream>>>(sems, psems);
    }

    paint_kernel<<<(N + 255) / 256, 256, 0, stream>>>(
        lidar, sems, psems, use_ps, Km, L2W, W2C, out, N);

    dim3 pb(64, 4, 1), pg(NTILE_X, NTILE_Y, HM_N);
    peaks15_kernel<<<pg, pb, 0, stream>>>(hm, s1score, s1idx);

    float* out_scores = out + (long long)N * NCH;
    float* out_locs   = out_scores + HM_N * MAX_DET_K;
    merge_kernel<<<HM_N, 1024, 0, stream>>>(s1score, s1idx, out_scores, out_locs);
}